// Round 7
// baseline (387.472 us; speedup 1.0000x reference)
//
#include <hip/hip_runtime.h>
#include <math.h>

#define BB 2
#define TT 2048
#define DD 1024
#define HH 16
#define INNERD 512
#define FFD 4096
#define NPROJ 2560     // D + 3*INNER
#define CATD2 2560     // 512 (attn) + 1024 (temporal) + 1024 (positional)
#define MROWS (BB*TT)  // 4096
#define CHUNK 64
#define NCH (TT/CHUNK) // 32
#define BH 32          // B*H

typedef __bf16 bf16;
typedef __attribute__((ext_vector_type(8))) __bf16 bf16x8;
typedef __attribute__((ext_vector_type(4))) __bf16 bf16x4;
typedef __attribute__((ext_vector_type(4))) float f32x4;

struct Part4 { void* p0; void* p1; void* p2; void* p3; };

// ---------------------------------------------------------------- fused prep:
// blocks [0,16):        bmix2 = b_mix + b_c @ W_mix[0:1024]  (FIRST: hides)
// blocks [16,528):      W_c fp32 -> bf16 cast
// blocks [528,4624):    LN1 row kernel
// blocks [4624,18448):  32x32 transpose tiles (f32x4 loads) for W_in, W_mix, W1, W2
__global__ __launch_bounds__(256) void prep_fused(
    const float* __restrict__ inputs, const float* __restrict__ ln1_g,
    const float* __restrict__ ln1_b, bf16* __restrict__ normed,
    const float* __restrict__ W_in,  bf16* __restrict__ wt_in,
    const float* __restrict__ W_mix, bf16* __restrict__ wt_m0,
    bf16* __restrict__ wt_comb,
    const float* __restrict__ W1,    bf16* __restrict__ wt1,
    const float* __restrict__ W2,    bf16* __restrict__ wt2,
    const float* __restrict__ W_c,   bf16* __restrict__ wc_b,
    const float* __restrict__ b_c,
    const float* __restrict__ b_mix, float* __restrict__ bmix2)
{
    int blk = blockIdx.x, tid = threadIdx.x;
    if (blk < 16) {
        int nl = tid & 63, jg = tid >> 6;
        int n = blk * 64 + nl;
        int j0 = jg * 256;
        float acc = 0.f;
        #pragma unroll 8
        for (int j = 0; j < 256; j++)
            acc = fmaf(b_c[j0 + j], W_mix[(size_t)(j0 + j) * DD + n], acc);
        __shared__ float red[4][64];
        red[jg][nl] = acc;
        __syncthreads();
        if (jg == 0)
            bmix2[n] = b_mix[n] + red[0][nl] + red[1][nl] + red[2][nl] + red[3][nl];
        return;
    }
    if (blk < 528) {             // W_c cast fp32 -> bf16
        int id = (blk - 16) * 256 + tid;
        f32x4 v = ((const f32x4*)W_c)[id];
        bf16x4 o;
        #pragma unroll
        for (int q = 0; q < 4; q++) o[q] = (bf16)v[q];
        ((bf16x4*)wc_b)[id] = o;
        return;
    }
    if (blk < 528 + MROWS) {
        // ---- LN1 ----
        int row = blk - 528;
        f32x4 xv = ((const f32x4*)(inputs + (size_t)row * DD))[tid];
        float s = xv[0] + xv[1] + xv[2] + xv[3];
        float s2 = xv[0]*xv[0] + xv[1]*xv[1] + xv[2]*xv[2] + xv[3]*xv[3];
        #pragma unroll
        for (int off = 32; off > 0; off >>= 1) {
            s  += __shfl_xor(s,  off, 64);
            s2 += __shfl_xor(s2, off, 64);
        }
        __shared__ float rs[4], rs2[4];
        int wid = tid >> 6;
        if ((tid & 63) == 0) { rs[wid] = s; rs2[wid] = s2; }
        __syncthreads();
        s  = rs[0] + rs[1] + rs[2] + rs[3];
        s2 = rs2[0] + rs2[1] + rs2[2] + rs2[3];
        float mean = s * (1.0f / DD);
        float var  = s2 * (1.0f / DD) - mean * mean;
        float rstd = rsqrtf(var + 1e-5f);
        f32x4 gv = ((const f32x4*)ln1_g)[tid];
        f32x4 bv = ((const f32x4*)ln1_b)[tid];
        bf16x4 o;
        #pragma unroll
        for (int q = 0; q < 4; q++)
            o[q] = (bf16)((xv[q] - mean) * rstd * gv[q] + bv[q]);
        ((bf16x4*)(normed + (size_t)row * DD))[tid] = o;
        return;
    }
    // ---- transpose fp32(K,N) -> bf16(N,K), 32x32 tiles, vectorized ----
    int tb = blk - (528 + MROWS);
    const float* W; bf16* Wt = nullptr; int Kd, Nd; bool is_mix = false;
    if      (tb < 2560)  {             W = W_in;  Wt = wt_in;  Kd = 1024; Nd = 2560; }
    else if (tb < 5632)  { tb -= 2560; W = W_mix;              Kd = 3072; Nd = 1024; is_mix = true; }
    else if (tb < 9728)  { tb -= 5632; W = W1;    Wt = wt1;    Kd = 1024; Nd = 4096; }
    else                 { tb -= 9728; W = W2;    Wt = wt2;    Kd = 4096; Nd = 1024; }
    int ntx = Nd >> 5;
    int nb = (tb % ntx) * 32, kb = (tb / ntx) * 32;
    int ldW = Kd, kw = kb;
    if (is_mix) {
        if (kb < 1024) { Wt = wt_m0;   ldW = 1024;  kw = kb; }
        else           { Wt = wt_comb; ldW = CATD2; kw = kb - 512; }  // cols 512..2559
    }
    __shared__ float t[32][33];
    int tx = tid & 7, ty = tid >> 3;    // 8 x 32; one f32x4 per thread
    f32x4 v = *(const f32x4*)(W + (size_t)(kb + ty) * Nd + nb + tx * 4);
    #pragma unroll
    for (int q = 0; q < 4; q++) t[ty][tx * 4 + q] = v[q];
    __syncthreads();
    bf16x4 o;
    #pragma unroll
    for (int q = 0; q < 4; q++) o[q] = (bf16)t[tx * 4 + q][ty];
    *(bf16x4*)(Wt + (size_t)(nb + ty) * ldW + kw + tx * 4) = o;
}

// ---------------------------------------------------------------- MFMA GEMM, BK=64, 4 blocks/CU
// (verified round-0 structure) — used for the mix GEMM.
// EPI 0: +bias   EPI 1: gelu(+bias)   EPI 4: bf16 partial -> part.p[z] (ldc=DD)
template<int EPI>
__global__ __launch_bounds__(256, 4) void gemm_mfma(
    const bf16* __restrict__ A,  int lda,
    const bf16* __restrict__ Bt, int ldb,
    const float* __restrict__ bias,
    bf16* __restrict__ Cb, int ldc,
    int K, Part4 part)
{
    __shared__ bf16 As[128 * 64];
    __shared__ bf16 Bs[128 * 64];
    const int tid  = threadIdx.x;
    const int wave = tid >> 6, lane = tid & 63;
    const int m0 = blockIdx.x * 128, n0 = blockIdx.y * 128;
    const int koff = blockIdx.z * K;
    A  += koff;
    Bt += koff;
    const int wr = wave >> 1, wc = wave & 1;
    const int lrow = lane >> 2;
    const int lcol = (lane & 3) * 8;
    const int fm = lane & 15;
    const int fk = (lane >> 4) * 8;

    f32x4 acc[4][4];
    #pragma unroll
    for (int i = 0; i < 4; i++)
        #pragma unroll
        for (int j = 0; j < 4; j++)
            acc[i][j] = (f32x4){0.f, 0.f, 0.f, 0.f};

    for (int k0 = 0; k0 < K; k0 += 64) {
        #pragma unroll
        for (int r = 0; r < 4; r++) {
            int c  = r * 4 + wave;
            int rc = c >> 1, kh = c & 1;
            const bf16* ga = A  + (size_t)(m0 + rc * 16 + lrow) * lda + k0 + kh * 32 + lcol;
            const bf16* gb = Bt + (size_t)(n0 + rc * 16 + lrow) * ldb + k0 + kh * 32 + lcol;
            __builtin_amdgcn_global_load_lds(
                (const __attribute__((address_space(1))) void*)ga,
                (__attribute__((address_space(3))) void*)(As + c * 512), 16, 0, 0);
            __builtin_amdgcn_global_load_lds(
                (const __attribute__((address_space(1))) void*)gb,
                (__attribute__((address_space(3))) void*)(Bs + c * 512), 16, 0, 0);
        }
        __syncthreads();
        #pragma unroll
        for (int ks = 0; ks < 2; ks++) {
            bf16x8 af[4], bfv[4];
            #pragma unroll
            for (int i = 0; i < 4; i++)
                af[i] = *(const bf16x8*)(As + (wr * 4 + i) * 1024 + ks * 512 + fm * 32 + fk);
            #pragma unroll
            for (int j = 0; j < 4; j++)
                bfv[j] = *(const bf16x8*)(Bs + (wc * 4 + j) * 1024 + ks * 512 + fm * 32 + fk);
            #pragma unroll
            for (int i = 0; i < 4; i++)
                #pragma unroll
                for (int j = 0; j < 4; j++)
                    acc[i][j] = __builtin_amdgcn_mfma_f32_16x16x32_bf16(
                        af[i], bfv[j], acc[i][j], 0, 0, 0);
        }
        __syncthreads();
    }

    void* psel = nullptr;
    if constexpr (EPI == 4) {
        int z = blockIdx.z;
        psel = (z == 0) ? part.p0 : (z == 1) ? part.p1 : (z == 2) ? part.p2 : part.p3;
    }

    #pragma unroll
    for (int i = 0; i < 4; i++) {
        int mbase = m0 + wr * 64 + i * 16 + (lane >> 4) * 4;
        #pragma unroll
        for (int j = 0; j < 4; j++) {
            int col = n0 + wc * 64 + j * 16 + (lane & 15);
            float bv = 0.f;
            if constexpr (EPI == 0 || EPI == 1) bv = bias[col];
            #pragma unroll
            for (int r = 0; r < 4; r++) {
                int row = mbase + r;
                float v = acc[i][j][r] + bv;
                if constexpr (EPI == 0) {
                    Cb[(size_t)row * ldc + col] = (bf16)v;
                } else if constexpr (EPI == 1) {
                    float z2 = v * (1.5957691f + 0.07135502f * v * v);
                    v = v / (1.0f + __expf(-z2));
                    Cb[(size_t)row * ldc + col] = (bf16)v;
                } else {
                    ((bf16*)psel)[(size_t)row * DD + col] = (bf16)v;
                }
            }
        }
    }
}

// ---------------------------------------------------------------- 256x256 8-phase MFMA GEMM (m201 template port)
// 512 thr = 8 waves (2M x 4N), BK=64, LDS 128 KiB = 2dbuf x 2half x (128x64) x {A,B}.
// Halftile layout: 16 subtiles of [16 rows][32 cols] bf16 (1024 B each), st_16x32
// swizzle within subtile: elem ^= ((row&8)?16:0) on the 16-elem chunk (byte bit5
// ^= row bit3). Each ds_read_b128 covers exactly one subtile (~4-way residual).
// Staging: global_load_lds linear dest (one subtile per call, lane l at l*16B);
// the swizzle involution is applied on the global SOURCE column.
// Schedule/K-tile (4 phases): p0 {B frags(8)+A q0(4) reads, stage A-h1 of t+1},
// p1 {A q1, stage B-h0 of t+2}, p2 {A q2, stage B-h1 of t+2}, p3 {A q3};
// A-h0 of t+2 staged after p3's barrier (fully read-complete). vmcnt(6) at
// tile end only (= 3 halftiles x 2 loads in flight -> 2 K-tiles of slack).
__device__ __forceinline__ void stage_half256(
    const bf16* __restrict__ src, int ld, int k0, int rowbase,
    bf16* ldsHalf, int wave, int sr, int sc)
{
    #pragma unroll
    for (int i = 0; i < 2; i++) {
        int s  = wave * 2 + i;          // subtile 0..15
        int rg = s >> 1, cg = s & 1;
        const bf16* g = src + (size_t)(rowbase + rg * 16 + sr) * ld + k0 + cg * 32 + sc;
        __builtin_amdgcn_global_load_lds(
            (const __attribute__((address_space(1))) void*)g,
            (__attribute__((address_space(3))) void*)(ldsHalf + s * 512), 16, 0, 0);
    }
}

template<int EPI>
__global__ __launch_bounds__(512) void gemm256(
    const bf16* __restrict__ A,  int lda,
    const bf16* __restrict__ Bt, int ldb,
    const float* __restrict__ bias,
    bf16* __restrict__ Cb, int ldc,
    int K, Part4 part)
{
    __shared__ bf16 sA[2 * 2 * 8192];   // [dbuf][half][subtiled 128x64]
    __shared__ bf16 sB[2 * 2 * 8192];
    const int tid  = threadIdx.x;
    const int wave = tid >> 6, lane = tid & 63;
    const int m0 = blockIdx.x * 256, n0 = blockIdx.y * 256;
    A  += (size_t)m0 * lda + (size_t)blockIdx.z * K;
    Bt += (size_t)n0 * ldb + (size_t)blockIdx.z * K;
    const int wr = wave >> 2, wc = wave & 3;     // 2 x 4 wave grid
    const int wcl = wc & 1;                      // B rowgroup base selector
    // staging lane decomposition (source-side inverse swizzle)
    const int sr = lane >> 2;                               // row in subtile
    const int sc = ((lane & 3) * 8) ^ ((sr & 8) ? 16 : 0);  // swizzled col elem
    // fragment read offset within a subtile (swizzled)
    const int fm = lane & 15;
    const int fro = ((fm * 32) + ((lane >> 4) * 8)) ^ ((fm & 8) ? 16 : 0);

    f32x4 acc[8][4];
    #pragma unroll
    for (int i = 0; i < 8; i++)
        #pragma unroll
        for (int j = 0; j < 4; j++)
            acc[i][j] = (f32x4){0.f, 0.f, 0.f, 0.f};

    const int NT = K >> 6;
    // ---- prologue: tile0 fully, tile1 {B-h0, B-h1, A-h0} ----
    stage_half256(Bt, ldb, 0, 0,   sB,          wave, sr, sc);
    stage_half256(Bt, ldb, 0, 128, sB + 8192,   wave, sr, sc);
    stage_half256(A,  lda, 0, 0,   sA,          wave, sr, sc);
    stage_half256(A,  lda, 0, 128, sA + 8192,   wave, sr, sc);
    if (NT > 1) {
        stage_half256(Bt, ldb, 64, 0,   sB + 16384, wave, sr, sc);
        stage_half256(Bt, ldb, 64, 128, sB + 24576, wave, sr, sc);
        stage_half256(A,  lda, 64, 0,   sA + 16384, wave, sr, sc);
        asm volatile("s_waitcnt vmcnt(6)" ::: "memory");   // tile0 landed
    } else {
        asm volatile("s_waitcnt vmcnt(0)" ::: "memory");
    }
    __builtin_amdgcn_s_barrier();

    for (int t = 0; t < NT; t++) {
        const int cur = t & 1, nxt = cur ^ 1;
        const bf16* pA = sA + (cur * 2 + wr) * 8192;         // this wave's A half
        const bf16* pB = sB + (cur * 2 + (wc >> 1)) * 8192;  // this wave's B half
        bf16* sAn1 = sA + (nxt * 2 + 1) * 8192;
        bf16* sBc0 = sB + (cur * 2 + 0) * 8192;
        bf16* sBc1 = sB + (cur * 2 + 1) * 8192;
        bf16* sAc0 = sA + (cur * 2 + 0) * 8192;
        const int kt1 = (t + 1) << 6, kt2 = (t + 2) << 6;
        bf16x8 bq[4][2];
        #pragma unroll
        for (int p = 0; p < 4; p++) {
            bf16x8 aq[2][2];
            if (p == 0) {
                #pragma unroll
                for (int j = 0; j < 4; j++)
                    #pragma unroll
                    for (int ks = 0; ks < 2; ks++)
                        bq[j][ks] = *(const bf16x8*)(pB + ((wcl * 4 + j) * 2 + ks) * 512 + fro);
            }
            #pragma unroll
            for (int ii = 0; ii < 2; ii++)
                #pragma unroll
                for (int ks = 0; ks < 2; ks++)
                    aq[ii][ks] = *(const bf16x8*)(pA + (((p * 2 + ii) * 2) + ks) * 512 + fro);
            if (p == 0) {
                if (t + 1 < NT) stage_half256(A, lda, kt1, 128, sAn1, wave, sr, sc);
                asm volatile("s_waitcnt lgkmcnt(8)" ::: "memory");
            } else if (p == 1) {
                if (t + 2 < NT) stage_half256(Bt, ldb, kt2, 0, sBc0, wave, sr, sc);
            } else if (p == 2) {
                if (t + 2 < NT) stage_half256(Bt, ldb, kt2, 128, sBc1, wave, sr, sc);
            }
            __builtin_amdgcn_s_barrier();
            asm volatile("s_waitcnt lgkmcnt(0)" ::: "memory");
            __builtin_amdgcn_sched_barrier(0);
            __builtin_amdgcn_s_setprio(1);
            #pragma unroll
            for (int ii = 0; ii < 2; ii++)
                #pragma unroll
                for (int j = 0; j < 4; j++)
                    #pragma unroll
                    for (int ks = 0; ks < 2; ks++)
                        acc[p * 2 + ii][j] = __builtin_amdgcn_mfma_f32_16x16x32_bf16(
                            aq[ii][ks], bq[j][ks], acc[p * 2 + ii][j], 0, 0, 0);
            __builtin_amdgcn_s_setprio(0);
            __builtin_amdgcn_s_barrier();
        }
        // A-h0 of t+2: staged only after phase-3's barrier (all reads of this
        // buffer complete across all waves) -> race-free by construction.
        if (t + 2 < NT) stage_half256(A, lda, kt2, 0, sAc0, wave, sr, sc);
        if (t + 1 < NT) {
            if (t + 2 < NT) asm volatile("s_waitcnt vmcnt(6)" ::: "memory");
            else            asm volatile("s_waitcnt vmcnt(0)" ::: "memory");
            __builtin_amdgcn_s_barrier();
        }
    }

    void* psel = nullptr;
    if constexpr (EPI == 4) {
        int z = blockIdx.z;
        psel = (z == 0) ? part.p0 : (z == 1) ? part.p1 : (z == 2) ? part.p2 : part.p3;
    }

    #pragma unroll
    for (int i = 0; i < 8; i++) {
        int mbase = m0 + wr * 128 + i * 16 + (lane >> 4) * 4;
        #pragma unroll
        for (int j = 0; j < 4; j++) {
            int col = n0 + wc * 64 + j * 16 + fm;
            float bv = 0.f;
            if constexpr (EPI == 0 || EPI == 1) bv = bias[col];
            #pragma unroll
            for (int r = 0; r < 4; r++) {
                int row = mbase + r;
                float v = acc[i][j][r] + bv;
                if constexpr (EPI == 0) {
                    Cb[(size_t)row * ldc + col] = (bf16)v;
                } else if constexpr (EPI == 1) {
                    float z2 = v * (1.5957691f + 0.07135502f * v * v);
                    v = v / (1.0f + __expf(-z2));
                    Cb[(size_t)row * ldc + col] = (bf16)v;
                } else {
                    ((bf16*)psel)[(size_t)row * DD + col] = (bf16)v;
                }
            }
        }
    }
}

// ---------------------------------------------------------------- proj GEMM with the tiny Wcm GEMM riding along.
__global__ __launch_bounds__(256, 4) void gemm_proj2(
    const bf16* __restrict__ normed, const bf16* __restrict__ wt_in,
    const float* __restrict__ bias,  bf16* __restrict__ proj,
    const bf16* __restrict__ wt_m0,  const bf16* __restrict__ wc_b,
    bf16* __restrict__ wt_comb)
{
    __shared__ bf16 As[128 * 64];
    __shared__ bf16 Bs[128 * 64];
    const int tid  = threadIdx.x;
    const int wave = tid >> 6, lane = tid & 63;
    const bool second = (blockIdx.y == 20);
    const bf16* A  = second ? wt_m0 : normed;
    const bf16* Bt = second ? wc_b  : wt_in;
    bf16* Cb       = second ? wt_comb : proj;
    const int m0 = second ? ((blockIdx.x >> 2) * 128) : (blockIdx.x * 128);
    const int n0 = second ? ((blockIdx.x & 3) * 128)  : (blockIdx.y * 128);
    const int wr = wave >> 1, wc = wave & 1;
    const int lrow = lane >> 2;
    const int lcol = (lane & 3) * 8;
    const int fm = lane & 15;
    const int fk = (lane >> 4) * 8;

    f32x4 acc[4][4];
    #pragma unroll
    for (int i = 0; i < 4; i++)
        #pragma unroll
        for (int j = 0; j < 4; j++)
            acc[i][j] = (f32x4){0.f, 0.f, 0.f, 0.f};

    for (int k0 = 0; k0 < DD; k0 += 64) {
        #pragma unroll
        for (int r = 0; r < 4; r++) {
            int c  = r * 4 + wave;
            int rc = c >> 1, kh = c & 1;
            const bf16* ga = A  + (size_t)(m0 + rc * 16 + lrow) * DD + k0 + kh * 32 + lcol;
            const bf16* gb = Bt + (size_t)(n0 + rc * 16 + lrow) * DD + k0 + kh * 32 + lcol;
            __builtin_amdgcn_global_load_lds(
                (const __attribute__((address_space(1))) void*)ga,
                (__attribute__((address_space(3))) void*)(As + c * 512), 16, 0, 0);
            __builtin_amdgcn_global_load_lds(
                (const __attribute__((address_space(1))) void*)gb,
                (__attribute__((address_space(3))) void*)(Bs + c * 512), 16, 0, 0);
        }
        __syncthreads();
        #pragma unroll
        for (int ks = 0; ks < 2; ks++) {
            bf16x8 af[4], bfv[4];
            #pragma unroll
            for (int i = 0; i < 4; i++)
                af[i] = *(const bf16x8*)(As + (wr * 4 + i) * 1024 + ks * 512 + fm * 32 + fk);
            #pragma unroll
            for (int j = 0; j < 4; j++)
                bfv[j] = *(const bf16x8*)(Bs + (wc * 4 + j) * 1024 + ks * 512 + fm * 32 + fk);
            #pragma unroll
            for (int i = 0; i < 4; i++)
                #pragma unroll
                for (int j = 0; j < 4; j++)
                    acc[i][j] = __builtin_amdgcn_mfma_f32_16x16x32_bf16(
                        af[i], bfv[j], acc[i][j], 0, 0, 0);
        }
        __syncthreads();
    }

    #pragma unroll
    for (int i = 0; i < 4; i++) {
        int mbase = m0 + wr * 64 + i * 16 + (lane >> 4) * 4;
        #pragma unroll
        for (int j = 0; j < 4; j++) {
            int col = n0 + wc * 64 + j * 16 + (lane & 15);
            float bv = second ? 0.f : bias[col];
            #pragma unroll
            for (int r = 0; r < 4; r++) {
                int row = mbase + r;
                Cb[(size_t)row * CATD2 + col] = (bf16)(acc[i][j][r] + bv);
            }
        }
    }
}

// ---------------------------------------------------------------- fused epilogue: mix (2 bf16 partials) gate + residual + mask, then LN2
__global__ __launch_bounds__(256) void epi_mix_ln2(
    const bf16* __restrict__ P0, const bf16* __restrict__ P1,
    const float* __restrict__ bias,
    const bf16* __restrict__ proj, const float* __restrict__ res,
    const float* __restrict__ mask,
    const float* __restrict__ g2, const float* __restrict__ b2v,
    float* __restrict__ out1, bf16* __restrict__ hbuf)
{
    int row = blockIdx.x, tid = threadIdx.x;
    float m = mask[row];
    size_t off = (size_t)row * DD + tid * 4;
    bf16x4 s0 = *(const bf16x4*)(P0 + off);
    bf16x4 s1 = *(const bf16x4*)(P1 + off);
    f32x4 bv = ((const f32x4*)bias)[tid];
    bf16x4 g4 = *(const bf16x4*)(proj + (size_t)row * NPROJ + tid * 4);
    f32x4 rv = ((const f32x4*)(res + (size_t)row * DD))[tid];
    f32x4 v;
    #pragma unroll
    for (int q = 0; q < 4; q++) {
        float sg = 1.0f / (1.0f + __expf(-(float)g4[q]));
        float sv = (float)s0[q] + (float)s1[q] + bv[q];
        v[q] = (rv[q] + sg * sv) * m;
    }
    ((f32x4*)(out1 + (size_t)row * DD))[tid] = v;
    // LN2
    float s = v[0] + v[1] + v[2] + v[3];
    float s2 = v[0]*v[0] + v[1]*v[1] + v[2]*v[2] + v[3]*v[3];
    #pragma unroll
    for (int off2 = 32; off2 > 0; off2 >>= 1) {
        s  += __shfl_xor(s,  off2, 64);
        s2 += __shfl_xor(s2, off2, 64);
    }
    __shared__ float rs[4], rs2[4];
    int wid = tid >> 6;
    if ((tid & 63) == 0) { rs[wid] = s; rs2[wid] = s2; }
    __syncthreads();
    s  = rs[0] + rs[1] + rs[2] + rs[3];
    s2 = rs2[0] + rs2[1] + rs2[2] + rs2[3];
    float mean = s * (1.0f / DD);
    float var  = s2 * (1.0f / DD) - mean * mean;
    float rstd = rsqrtf(var + 1e-5f);
    f32x4 gg = ((const f32x4*)g2)[tid];
    f32x4 bb = ((const f32x4*)b2v)[tid];
    bf16x4 h;
    #pragma unroll
    for (int q = 0; q < 4; q++)
        h[q] = (bf16)((v[q] - mean) * rstd * gg[q] + bb[q]);
    ((bf16x4*)(hbuf + (size_t)row * DD))[tid] = h;
}

// ---------------------------------------------------------------- final epilogue: out = (out1 + sum 4 bf16 partials + b2) * mask
__global__ __launch_bounds__(256) void epi_w2(
    float* __restrict__ d_out, const float* __restrict__ out1,
    const bf16* __restrict__ P0, const bf16* __restrict__ P1,
    const bf16* __restrict__ P2, const bf16* __restrict__ P3,
    const float* __restrict__ bias, const float* __restrict__ mask)
{
    int id = blockIdx.x * 256 + threadIdx.x;
    int row = id >> 8;
    float m = mask[row];
    bf16x4 a0 = ((const bf16x4*)P0)[id];
    bf16x4 a1 = ((const bf16x4*)P1)[id];
    bf16x4 a2 = ((const bf16x4*)P2)[id];
    bf16x4 a3 = ((const bf16x4*)P3)[id];
    f32x4 r = ((const f32x4*)out1)[id];
    f32x4 b = ((const f32x4*)bias)[id & 255];
    f32x4 o;
    #pragma unroll
    for (int q = 0; q < 4; q++) {
        float sv = (float)a0[q] + (float)a1[q] + (float)a2[q] + (float)a3[q];
        o[q] = (r[q] + sv + b[q]) * m;
    }
    ((f32x4*)d_out)[id] = o;
}

// ---------------------------------------------------------------- attention helpers
__device__ __forceinline__ float phi_f(float x) {
    return x > 0.f ? x + 1.f : __expf(x);   // elu(x)+1
}

// ---------------------------------------------------------------- mid fused
__global__ __launch_bounds__(256) void mid_fused(
    const bf16* __restrict__ x,
    const float* __restrict__ w_t, const float* __restrict__ b_t,
    const float* __restrict__ w_p, const float* __restrict__ b_p,
    bf16* __restrict__ cat,
    const bf16* __restrict__ proj, const float* __restrict__ mask,
    float* __restrict__ kvsum, float* __restrict__ kssum)
{
    __shared__ float s_ks[2][CHUNK][32], s_vs[2][CHUNK][32];   // 32 KB
    int blk = blockIdx.x, tid = threadIdx.x;
    if (blk < 1024) {
        // ---- dwconv ----
        int id = blk * 256 + tid;
        int cg = id & 127, rp = id >> 7;
        int c0 = cg * 8;
        int row0 = rp * 2;
        int t0 = row0 & (TT - 1);
        bf16x8 xw[16];
        #pragma unroll
        for (int j = 0; j < 16; j++) {
            int t = t0 - 14 + j;
            if (t >= 0)
                xw[j] = *(const bf16x8*)(x + (size_t)(row0 - 14 + j) * DD + c0);
            else
                #pragma unroll
                for (int q = 0; q < 8; q++) xw[j][q] = (bf16)0.f;
        }
        float y15[2][8], y3[2][8];
        #pragma unroll
        for (int q = 0; q < 8; q++) {
            float bp = b_p[c0 + q], bt = b_t[c0 + q];
            y15[0][q] = bp; y15[1][q] = bp;
            y3[0][q] = bt;  y3[1][q] = bt;
        }
        #pragma unroll
        for (int i = 0; i < 15; i++) {
            float wp[8];
            #pragma unroll
            for (int q = 0; q < 8; q++) wp[q] = w_p[(c0 + q) * 15 + i];
            #pragma unroll
            for (int rr = 0; rr < 2; rr++)
                #pragma unroll
                for (int q = 0; q < 8; q++)
                    y15[rr][q] = fmaf(wp[q], (float)xw[rr + i][q], y15[rr][q]);
        }
        #pragma unroll
        for (int i = 0; i < 3; i++) {
            float wt[8];
            #pragma unroll
            for (int q = 0; q < 8; q++) wt[q] = w_t[(c0 + q) * 3 + i];
            #pragma unroll
            for (int rr = 0; rr < 2; rr++)
                #pragma unroll
                for (int q = 0; q < 8; q++)
                    y3[rr][q] = fmaf(wt[q], (float)xw[rr + 12 + i][q], y3[rr][q]);
        }
        #pragma unroll
        for (int rr = 0; rr < 2; rr++) {
            bf16x8 o3, o15;
            #pragma unroll
            for (int q = 0; q < 8; q++) { o3[q] = (bf16)y3[rr][q]; o15[q] = (bf16)y15[rr][q]; }
            *(bf16x8*)(cat + (size_t)(row0 + rr) * CATD2 + 512 + c0)  = o3;
            *(bf16x8*)(cat + (size_t)(row0 + rr) * CATD2 + 1536 + c0) = o15;
        }
        return;
    }
    // ---- attn phase A ----
    int w = tid >> 6;
    if (w >= 2) return;
    int lane = tid & 63;
    int ci = (blk - 1024) * 2 + w;
    int c  = ci & (NCH - 1);
    int bh = ci >> 5;
    int b  = bh >> 4, hh = bh & (HH - 1);
    float (*ks)[32] = s_ks[w];
    float (*vs)[32] = s_vs[w];
    int row0 = b * TT + c * CHUNK;
    {
        int row = row0 + lane;
        float m = mask[row];
        const bf16* kp = proj + (size_t)row * NPROJ + DD + INNERD + hh * 32;
        const bf16* vp = kp + INNERD;
        #pragma unroll
        for (int s = 0; s < 4; s++) {
            bf16x8 k8 = *(const bf16x8*)(kp + s * 8);
            bf16x8 v8 = *(const bf16x8*)(vp + s * 8);
            #pragma unroll
            for (int q = 0; q < 8; q++) {
                ks[lane][s * 8 + q] = phi_f((float)k8[q]) * m;
                vs[lane][s * 8 + q] = (float)v8[q] * m;
            }
        }
    }
    int e = lane & 31, d0 = (lane >> 5) * 16;
    float kv[16], ksl[16];
    #pragma unroll
    for (int j = 0; j < 16; j++) { kv[j] = 0.f; ksl[j] = 0.f; }
    for (int t = 0; t < CHUNK; t++) {
        float ve = vs[t][e];
        f32x4 kr[4];
        #pragma unroll
        for (int s = 0; s < 4; s++) kr[s] = *(const f32x4*)&ks[t][d0 + s * 4];
        #pragma unroll
        for (int j = 0; j < 16; j++) {
            float kval = kr[j >> 2][j & 3];
            kv[j] = fmaf(kval, ve, kv[j]);
            ksl[j] += kval;
        }
    }
    size_t base = (size_t)ci * 1024;
    #pragma unroll
    for (int j = 0; j < 16; j++)
        kvsum[base + (size_t)(d0 + j) * 32 + e] = kv[j];
    if (e == 0) {
        #pragma unroll
        for (int j = 0; j < 16; j++)
            kssum[ci * 32 + d0 + j] = ksl[j];
    }
}

// Phase B: exclusive prefix over chunks — parallel (one scan per thread).
__global__ __launch_bounds__(256) void attn_prefix(
    const float* __restrict__ kvsum, const float* __restrict__ kssum,
    float* __restrict__ kvpref, float* __restrict__ kspref)
{
    int blk = blockIdx.x, tid = threadIdx.x;
    if (blk < 128) {
        int bh = blk >> 2;
        int de = (blk & 3) * 256 + tid;
        float run = 0.f;
        for (int c = 0; c < NCH; c++) {
            size_t a = (size_t)(bh * NCH + c) * 1024 + de;
            kvpref[a] = run;
            run += kvsum[a];
        }
        return;
    }
    int id = (blk - 128) * 256 + tid;
    int bh = id >> 5, d = id & 31;
    float r = 0.f;
    for (int c = 0; c < NCH; c++) {
        int a = (bh * NCH + c) * 32 + d;
        kspref[a] = r;
        r += kssum[a];
    }
}

// Phase C: in-chunk scan, LDS-resident. Writes attn output into cat[:,0:512).
__global__ __launch_bounds__(64) void attn_scan(
    const bf16* __restrict__ proj, const float* __restrict__ mask,
    const float* __restrict__ kvpref, const float* __restrict__ kspref,
    bf16* __restrict__ cat)
{
    int blk = blockIdx.x;
    int c  = blk & (NCH - 1);
    int bh = blk >> 5;
    int b  = bh >> 4, hh = bh & (HH - 1);
    int lane = threadIdx.x;
    __shared__ float qs[CHUNK][32], ks[CHUNK][32], vs[CHUNK][32];
    __shared__ float ms[CHUNK];
    int row0 = b * TT + c * CHUNK;
    {
        int row = row0 + lane;
        float m = mask[row];
        ms[lane] = m;
        const bf16* qp = proj + (size_t)row * NPROJ + DD + hh * 32;
        const bf16* kp = qp + INNERD;
        const bf16* vp = kp + INNERD;
        #pragma unroll
        for (int s = 0; s < 4; s++) {
            bf16x8 q8 = *(const bf16x8*)(qp + s * 8);
            bf16x8 k8 = *(const bf16x8*)(kp + s * 8);
            bf16x8 v8 = *(const bf16x8*)(vp + s * 8);
            #pragma unroll
            for (int q = 0; q < 8; q++) {
                qs[lane][s * 8 + q] = phi_f((float)q8[q]) * m;
                ks[lane][s * 8 + q] = phi_f((float)k8[q]) * m;
                vs[lane][s * 8 + q] = (float)v8[q] * m;
            }
        }
    }
    int e = lane & 31, d0 = (lane >> 5) * 16;
    float kv[16], ksl[16];
    size_t base = (size_t)blk * 1024;
    #pragma unroll
    for (int j = 0; j < 16; j++) kv[j] = kvpref[base + (size_t)(d0 + j) * 32 + e];
    #pragma unroll
    for (int j = 0; j < 16; j++) ksl[j] = kspref[blk * 32 + d0 + j];
    __syncthreads();
    for (int t = 0; t < CHUNK; t++) {
        float ve = vs[t][e];
        f32x4 kr[4], qr[4];
        #pragma unroll
        for (int s = 0; s < 4; s++) kr[s] = *(const f32x4*)&ks[t][d0 + s * 4];
        #pragma unroll
        for (int s = 0; s < 4; s++) qr[s] = *(const f32x4*)&qs[t][d0 + s * 4];
        float num0 = 0.f, num1 = 0.f, den0 = 0.f, den1 = 0.f;
        #pragma unroll
        for (int j = 0; j < 16; j++) {
            float kval = kr[j >> 2][j & 3], qval = qr[j >> 2][j & 3];
            kv[j]  = fmaf(kval, ve, kv[j]);
            ksl[j] += kval;
            if (j & 1) { num1 = fmaf(qval, kv[j], num1); den1 = fmaf(qval, ksl[j], den1); }
            else       { num0 = fmaf(qval, kv[j], num0); den0 = fmaf(qval, ksl[j], den0); }
        }
        float num = num0 + num1, den = den0 + den1;
        num += __shfl_xor(num, 32, 64);
        den += __shfl_xor(den, 32, 64);
        if (lane < 32)
            cat[(size_t)(row0 + t) * CATD2 + hh * 32 + e] =
                (bf16)(num / (den + 1e-6f) * ms[t]);
    }
}

// ---------------------------------------------------------------- launch
extern "C" void kernel_launch(void* const* d_in, const int* in_sizes, int n_in,
                              void* d_out, int out_size, void* d_ws, size_t ws_size,
                              hipStream_t stream)
{
    const float* inputs = (const float*)d_in[0];
    const float* mask   = (const float*)d_in[1];
    const float* ln1_g  = (const float*)d_in[2];
    const float* ln1_b  = (const float*)d_in[3];
    const float* W_in   = (const float*)d_in[4];
    const float* b_in   = (const float*)d_in[5];
    const float* W_c    = (const float*)d_in[6];
    const float* b_c    = (const float*)d_in[7];
    const float* w_t    = (const float*)d_in[8];
    const float* b_t    = (const float*)d_in[9];
    const float* w_p    = (const float*)d_in[10];
    const float* b_p    = (const float*)d_in[11];
    const float* W_mix  = (const float*)d_in[12];
    const float* b_mix  = (const float*)d_in[13];
    const float* ln2_g  = (const float*)d_in[14];
    const float* ln2_b  = (const float*)d_in[15];
    const float* W1     = (const float*)d_in[16];
    const float* b1     = (const float*)d_in[17];
    const float* W2     = (const float*)d_in[18];
    const float* b2     = (const float*)d_in[19];
    float* out = (float*)d_out;

    // workspace layout (MiB offsets): see round-4 comment; unchanged.
    char* p = (char*)d_ws;
    bf16* normed = (bf16*)p;  p += (size_t)MROWS * DD * 2;       // 8 MiB
    bf16* proj   = (bf16*)p;  p += (size_t)MROWS * NPROJ * 2;    // 20 MiB
    bf16* cat    = (bf16*)p;  p += (size_t)MROWS * CATD2 * 2;    // 20 MiB
    float* out1  = (float*)p; p += (size_t)MROWS * DD * 4;       // 16 MiB
    bf16* hbuf   = (bf16*)p;  p += (size_t)MROWS * DD * 2;       // 8 MiB
    bf16* wt_in  = (bf16*)p;  p += (size_t)NPROJ * DD * 2;       // 5 MiB
    bf16* wt_m0  = (bf16*)p;  p += (size_t)DD * DD * 2;          // 2 MiB
    bf16* wt_comb= (bf16*)p;  p += (size_t)DD * CATD2 * 2;       // 5 MiB
    bf16* wt1    = (bf16*)p;  p += (size_t)FFD * DD * 2;         // 8 MiB
    bf16* wt2    = (bf16*)p;  p += (size_t)DD * FFD * 2;         // 8 MiB
    bf16* wc_b   = (bf16*)p;  p += (size_t)INNERD * DD * 2;      // 1 MiB
    float* bmix2 = (float*)p; p += (size_t)DD * 4;               // 4 KiB
    bf16* ffn1   = (bf16*)d_ws;                  // alias [normed|proj|cat-head]
    float* kvsum = out1;                         // alias out1 region (attn)
    float* kvpref= kvsum  + (size_t)BH * NCH * 1024;
    float* kssum = kvpref + (size_t)BH * NCH * 1024;
    float* kspref= kssum  + (size_t)BH * NCH * 32;
    // split-K bf16 partials
    bf16*  m_p0  = (bf16*)d_out;
    bf16*  m_p1  = (bf16*)d_out + (size_t)MROWS * DD;
    bf16*  w2_p0 = (bf16*)((char*)cat + ((size_t)4  << 20));  // abs [32,40) MiB
    bf16*  w2_p1 = (bf16*)((char*)cat + ((size_t)12 << 20));  // abs [40,48) MiB
    bf16*  w2_p2 = wt1;
    bf16*  w2_p3 = hbuf;

    // 1. fused prep: bmix2 fold (first!) + W_c cast + LN1 + weight transposes
    prep_fused<<<16 + 512 + MROWS + 13824, 256, 0, stream>>>(
        inputs, ln1_g, ln1_b, normed,
        W_in, wt_in, W_mix, wt_m0, wt_comb, W1, wt1, W2, wt2,
        W_c, wc_b, b_c, b_mix, bmix2);
    // 2. proj = normed @ W_in + b_in  (+ Wcm GEMM riding in by==20 row)
    gemm_proj2<<<dim3(MROWS/128, NPROJ/128 + 1), 256, 0, stream>>>(
        normed, wt_in, b_in, proj, wt_m0, wc_b, wt_comb);
    // 3. fused dwconv + attn phase A
    mid_fused<<<1024 + 512, 256, 0, stream>>>(
        normed, w_t, b_t, w_p, b_p, cat, proj, mask, kvsum, kssum);
    // 4-5. prefix + scan (scan writes cat[:,0:512))
    attn_prefix<<<132, 256, 0, stream>>>(kvsum, kssum, kvpref, kspref);
    attn_scan  <<<BH * NCH, 64, 0, stream>>>(proj, mask, kvpref, kspref, cat);
    // 6. mix split-2 bf16 partials: cat(2560) @ wt_comb
    gemm_mfma<4><<<dim3(MROWS/128, DD/128, 2), 256, 0, stream>>>(
        cat, CATD2, wt_comb, CATD2, nullptr, nullptr, DD, CATD2 / 2,
        Part4{m_p0, m_p1, nullptr, nullptr});
    // 7. out1 = (inputs + sigmoid(gate)*(P0+P1+bmix2))*mask ; hbuf = LN2(out1)
    epi_mix_ln2<<<MROWS, 256, 0, stream>>>(m_p0, m_p1, bmix2, proj, inputs,
                                           mask, ln2_g, ln2_b, out1, hbuf);
    // 8. ffn1 = gelu(hbuf @ W1 + b1)   [8-phase 256² kernel, grid = 256 = 1/CU]
    gemm256<1><<<dim3(MROWS/256, FFD/256), 512, 0, stream>>>(
        hbuf, DD, wt1, DD, b1, ffn1, FFD, DD, Part4{});
    // 9. W2 split-4 bf16 partials      [8-phase 256² kernel, grid = 256 = 1/CU]
    gemm256<4><<<dim3(MROWS/256, DD/256, 4), 512, 0, stream>>>(
        ffn1, FFD, wt2, FFD, nullptr, nullptr, DD, FFD / 4,
        Part4{w2_p0, w2_p1, w2_p2, w2_p3});
    // 10. out = (out1 + sum P + b2) * mask
    epi_w2<<<MROWS * DD / 4 / 256, 256, 0, stream>>>(out, out1, w2_p0, w2_p1,
                                                     w2_p2, w2_p3, b2, mask);
}

// Round 8
// 375.021 us; speedup vs baseline: 1.0332x; 1.0332x over previous
//
#include <hip/hip_runtime.h>
#include <math.h>

#define BB 2
#define TT 2048
#define DD 1024
#define HH 16
#define INNERD 512
#define FFD 4096
#define NPROJ 2560     // D + 3*INNER
#define CATD2 2560     // 512 (attn) + 1024 (temporal) + 1024 (positional)
#define MROWS (BB*TT)  // 4096
#define CHUNK 64
#define NCH (TT/CHUNK) // 32
#define BH 32          // B*H

typedef __bf16 bf16;
typedef __attribute__((ext_vector_type(8))) __bf16 bf16x8;
typedef __attribute__((ext_vector_type(4))) __bf16 bf16x4;
typedef __attribute__((ext_vector_type(4))) float f32x4;

struct Part4 { void* p0; void* p1; void* p2; void* p3; };

// ---------------------------------------------------------------- fused prep:
// blocks [0,16):        bmix2 = b_mix + b_c @ W_mix[0:1024]  (FIRST: hides)
// blocks [16,528):      W_c fp32 -> bf16 cast
// blocks [528,4624):    LN1 row kernel
// blocks [4624,18448):  32x32 transpose tiles (f32x4 loads) for W_in, W_mix, W1, W2
__global__ __launch_bounds__(256) void prep_fused(
    const float* __restrict__ inputs, const float* __restrict__ ln1_g,
    const float* __restrict__ ln1_b, bf16* __restrict__ normed,
    const float* __restrict__ W_in,  bf16* __restrict__ wt_in,
    const float* __restrict__ W_mix, bf16* __restrict__ wt_m0,
    bf16* __restrict__ wt_comb,
    const float* __restrict__ W1,    bf16* __restrict__ wt1,
    const float* __restrict__ W2,    bf16* __restrict__ wt2,
    const float* __restrict__ W_c,   bf16* __restrict__ wc_b,
    const float* __restrict__ b_c,
    const float* __restrict__ b_mix, float* __restrict__ bmix2)
{
    int blk = blockIdx.x, tid = threadIdx.x;
    if (blk < 16) {
        int nl = tid & 63, jg = tid >> 6;
        int n = blk * 64 + nl;
        int j0 = jg * 256;
        float acc = 0.f;
        #pragma unroll 8
        for (int j = 0; j < 256; j++)
            acc = fmaf(b_c[j0 + j], W_mix[(size_t)(j0 + j) * DD + n], acc);
        __shared__ float red[4][64];
        red[jg][nl] = acc;
        __syncthreads();
        if (jg == 0)
            bmix2[n] = b_mix[n] + red[0][nl] + red[1][nl] + red[2][nl] + red[3][nl];
        return;
    }
    if (blk < 528) {             // W_c cast fp32 -> bf16
        int id = (blk - 16) * 256 + tid;
        f32x4 v = ((const f32x4*)W_c)[id];
        bf16x4 o;
        #pragma unroll
        for (int q = 0; q < 4; q++) o[q] = (bf16)v[q];
        ((bf16x4*)wc_b)[id] = o;
        return;
    }
    if (blk < 528 + MROWS) {
        // ---- LN1 ----
        int row = blk - 528;
        f32x4 xv = ((const f32x4*)(inputs + (size_t)row * DD))[tid];
        float s = xv[0] + xv[1] + xv[2] + xv[3];
        float s2 = xv[0]*xv[0] + xv[1]*xv[1] + xv[2]*xv[2] + xv[3]*xv[3];
        #pragma unroll
        for (int off = 32; off > 0; off >>= 1) {
            s  += __shfl_xor(s,  off, 64);
            s2 += __shfl_xor(s2, off, 64);
        }
        __shared__ float rs[4], rs2[4];
        int wid = tid >> 6;
        if ((tid & 63) == 0) { rs[wid] = s; rs2[wid] = s2; }
        __syncthreads();
        s  = rs[0] + rs[1] + rs[2] + rs[3];
        s2 = rs2[0] + rs2[1] + rs2[2] + rs2[3];
        float mean = s * (1.0f / DD);
        float var  = s2 * (1.0f / DD) - mean * mean;
        float rstd = rsqrtf(var + 1e-5f);
        f32x4 gv = ((const f32x4*)ln1_g)[tid];
        f32x4 bv = ((const f32x4*)ln1_b)[tid];
        bf16x4 o;
        #pragma unroll
        for (int q = 0; q < 4; q++)
            o[q] = (bf16)((xv[q] - mean) * rstd * gv[q] + bv[q]);
        ((bf16x4*)(normed + (size_t)row * DD))[tid] = o;
        return;
    }
    // ---- transpose fp32(K,N) -> bf16(N,K), 32x32 tiles, vectorized ----
    int tb = blk - (528 + MROWS);
    const float* W; bf16* Wt = nullptr; int Kd, Nd; bool is_mix = false;
    if      (tb < 2560)  {             W = W_in;  Wt = wt_in;  Kd = 1024; Nd = 2560; }
    else if (tb < 5632)  { tb -= 2560; W = W_mix;              Kd = 3072; Nd = 1024; is_mix = true; }
    else if (tb < 9728)  { tb -= 5632; W = W1;    Wt = wt1;    Kd = 1024; Nd = 4096; }
    else                 { tb -= 9728; W = W2;    Wt = wt2;    Kd = 4096; Nd = 1024; }
    int ntx = Nd >> 5;
    int nb = (tb % ntx) * 32, kb = (tb / ntx) * 32;
    int ldW = Kd, kw = kb;
    if (is_mix) {
        if (kb < 1024) { Wt = wt_m0;   ldW = 1024;  kw = kb; }
        else           { Wt = wt_comb; ldW = CATD2; kw = kb - 512; }  // cols 512..2559
    }
    __shared__ float t[32][33];
    int tx = tid & 7, ty = tid >> 3;    // 8 x 32; one f32x4 per thread
    f32x4 v = *(const f32x4*)(W + (size_t)(kb + ty) * Nd + nb + tx * 4);
    #pragma unroll
    for (int q = 0; q < 4; q++) t[ty][tx * 4 + q] = v[q];
    __syncthreads();
    bf16x4 o;
    #pragma unroll
    for (int q = 0; q < 4; q++) o[q] = (bf16)t[tx * 4 + q][ty];
    *(bf16x4*)(Wt + (size_t)(nb + ty) * ldW + kw + tx * 4) = o;
}

// ---------------------------------------------------------------- MFMA GEMM, BK=64, 4 blocks/CU
// (verified round-0 structure: 128x128 tile, 2-barrier K-loop, global_load_lds w16)
// EPI 0: +bias   EPI 1: gelu(+bias)   EPI 4: bf16 partial -> part.p[z] (ldc=DD)
template<int EPI>
__global__ __launch_bounds__(256, 4) void gemm_mfma(
    const bf16* __restrict__ A,  int lda,
    const bf16* __restrict__ Bt, int ldb,
    const float* __restrict__ bias,
    bf16* __restrict__ Cb, int ldc,
    int K, Part4 part)
{
    __shared__ bf16 As[128 * 64];
    __shared__ bf16 Bs[128 * 64];
    const int tid  = threadIdx.x;
    const int wave = tid >> 6, lane = tid & 63;
    const int m0 = blockIdx.x * 128, n0 = blockIdx.y * 128;
    const int koff = blockIdx.z * K;
    A  += koff;
    Bt += koff;
    const int wr = wave >> 1, wc = wave & 1;
    const int lrow = lane >> 2;
    const int lcol = (lane & 3) * 8;
    const int fm = lane & 15;
    const int fk = (lane >> 4) * 8;

    f32x4 acc[4][4];
    #pragma unroll
    for (int i = 0; i < 4; i++)
        #pragma unroll
        for (int j = 0; j < 4; j++)
            acc[i][j] = (f32x4){0.f, 0.f, 0.f, 0.f};

    for (int k0 = 0; k0 < K; k0 += 64) {
        #pragma unroll
        for (int r = 0; r < 4; r++) {
            int c  = r * 4 + wave;
            int rc = c >> 1, kh = c & 1;
            const bf16* ga = A  + (size_t)(m0 + rc * 16 + lrow) * lda + k0 + kh * 32 + lcol;
            const bf16* gb = Bt + (size_t)(n0 + rc * 16 + lrow) * ldb + k0 + kh * 32 + lcol;
            __builtin_amdgcn_global_load_lds(
                (const __attribute__((address_space(1))) void*)ga,
                (__attribute__((address_space(3))) void*)(As + c * 512), 16, 0, 0);
            __builtin_amdgcn_global_load_lds(
                (const __attribute__((address_space(1))) void*)gb,
                (__attribute__((address_space(3))) void*)(Bs + c * 512), 16, 0, 0);
        }
        __syncthreads();
        #pragma unroll
        for (int ks = 0; ks < 2; ks++) {
            bf16x8 af[4], bfv[4];
            #pragma unroll
            for (int i = 0; i < 4; i++)
                af[i] = *(const bf16x8*)(As + (wr * 4 + i) * 1024 + ks * 512 + fm * 32 + fk);
            #pragma unroll
            for (int j = 0; j < 4; j++)
                bfv[j] = *(const bf16x8*)(Bs + (wc * 4 + j) * 1024 + ks * 512 + fm * 32 + fk);
            #pragma unroll
            for (int i = 0; i < 4; i++)
                #pragma unroll
                for (int j = 0; j < 4; j++)
                    acc[i][j] = __builtin_amdgcn_mfma_f32_16x16x32_bf16(
                        af[i], bfv[j], acc[i][j], 0, 0, 0);
        }
        __syncthreads();
    }

    void* psel = nullptr;
    if constexpr (EPI == 4) {
        int z = blockIdx.z;
        psel = (z == 0) ? part.p0 : (z == 1) ? part.p1 : (z == 2) ? part.p2 : part.p3;
    }

    #pragma unroll
    for (int i = 0; i < 4; i++) {
        int mbase = m0 + wr * 64 + i * 16 + (lane >> 4) * 4;
        #pragma unroll
        for (int j = 0; j < 4; j++) {
            int col = n0 + wc * 64 + j * 16 + (lane & 15);
            float bv = 0.f;
            if constexpr (EPI == 0 || EPI == 1) bv = bias[col];
            #pragma unroll
            for (int r = 0; r < 4; r++) {
                int row = mbase + r;
                float v = acc[i][j][r] + bv;
                if constexpr (EPI == 0) {
                    Cb[(size_t)row * ldc + col] = (bf16)v;
                } else if constexpr (EPI == 1) {
                    float z2 = v * (1.5957691f + 0.07135502f * v * v);
                    v = v / (1.0f + __expf(-z2));
                    Cb[(size_t)row * ldc + col] = (bf16)v;
                } else {
                    ((bf16*)psel)[(size_t)row * DD + col] = (bf16)v;
                }
            }
        }
    }
}

// ---------------------------------------------------------------- proj GEMM with the tiny Wcm GEMM riding along.
// Grid (32, 21). by<20: proj = normed @ wt_in + b_in  (C=proj, ldc=2560).
// by==20 (32 blocks, fills idle co-residency slots): wt_comb[:,0:512] =
//   (W_c @ Wm0)^T via A=wt_m0, B=wc_b (C=wt_comb, ldc=2560, no bias).
__global__ __launch_bounds__(256, 4) void gemm_proj2(
    const bf16* __restrict__ normed, const bf16* __restrict__ wt_in,
    const float* __restrict__ bias,  bf16* __restrict__ proj,
    const bf16* __restrict__ wt_m0,  const bf16* __restrict__ wc_b,
    bf16* __restrict__ wt_comb)
{
    __shared__ bf16 As[128 * 64];
    __shared__ bf16 Bs[128 * 64];
    const int tid  = threadIdx.x;
    const int wave = tid >> 6, lane = tid & 63;
    const bool second = (blockIdx.y == 20);
    const bf16* A  = second ? wt_m0 : normed;
    const bf16* Bt = second ? wc_b  : wt_in;
    bf16* Cb       = second ? wt_comb : proj;
    const int m0 = second ? ((blockIdx.x >> 2) * 128) : (blockIdx.x * 128);
    const int n0 = second ? ((blockIdx.x & 3) * 128)  : (blockIdx.y * 128);
    const int wr = wave >> 1, wc = wave & 1;
    const int lrow = lane >> 2;
    const int lcol = (lane & 3) * 8;
    const int fm = lane & 15;
    const int fk = (lane >> 4) * 8;

    f32x4 acc[4][4];
    #pragma unroll
    for (int i = 0; i < 4; i++)
        #pragma unroll
        for (int j = 0; j < 4; j++)
            acc[i][j] = (f32x4){0.f, 0.f, 0.f, 0.f};

    for (int k0 = 0; k0 < DD; k0 += 64) {
        #pragma unroll
        for (int r = 0; r < 4; r++) {
            int c  = r * 4 + wave;
            int rc = c >> 1, kh = c & 1;
            const bf16* ga = A  + (size_t)(m0 + rc * 16 + lrow) * DD + k0 + kh * 32 + lcol;
            const bf16* gb = Bt + (size_t)(n0 + rc * 16 + lrow) * DD + k0 + kh * 32 + lcol;
            __builtin_amdgcn_global_load_lds(
                (const __attribute__((address_space(1))) void*)ga,
                (__attribute__((address_space(3))) void*)(As + c * 512), 16, 0, 0);
            __builtin_amdgcn_global_load_lds(
                (const __attribute__((address_space(1))) void*)gb,
                (__attribute__((address_space(3))) void*)(Bs + c * 512), 16, 0, 0);
        }
        __syncthreads();
        #pragma unroll
        for (int ks = 0; ks < 2; ks++) {
            bf16x8 af[4], bfv[4];
            #pragma unroll
            for (int i = 0; i < 4; i++)
                af[i] = *(const bf16x8*)(As + (wr * 4 + i) * 1024 + ks * 512 + fm * 32 + fk);
            #pragma unroll
            for (int j = 0; j < 4; j++)
                bfv[j] = *(const bf16x8*)(Bs + (wc * 4 + j) * 1024 + ks * 512 + fm * 32 + fk);
            #pragma unroll
            for (int i = 0; i < 4; i++)
                #pragma unroll
                for (int j = 0; j < 4; j++)
                    acc[i][j] = __builtin_amdgcn_mfma_f32_16x16x32_bf16(
                        af[i], bfv[j], acc[i][j], 0, 0, 0);
        }
        __syncthreads();
    }

    #pragma unroll
    for (int i = 0; i < 4; i++) {
        int mbase = m0 + wr * 64 + i * 16 + (lane >> 4) * 4;
        #pragma unroll
        for (int j = 0; j < 4; j++) {
            int col = n0 + wc * 64 + j * 16 + (lane & 15);
            float bv = second ? 0.f : bias[col];
            #pragma unroll
            for (int r = 0; r < 4; r++) {
                int row = mbase + r;
                Cb[(size_t)row * CATD2 + col] = (bf16)(acc[i][j][r] + bv);
            }
        }
    }
}

// ---------------------------------------------------------------- fused epilogue: mix (2 bf16 partials) gate + residual + mask, then LN2
__global__ __launch_bounds__(256) void epi_mix_ln2(
    const bf16* __restrict__ P0, const bf16* __restrict__ P1,
    const float* __restrict__ bias,
    const bf16* __restrict__ proj, const float* __restrict__ res,
    const float* __restrict__ mask,
    const float* __restrict__ g2, const float* __restrict__ b2v,
    float* __restrict__ out1, bf16* __restrict__ hbuf)
{
    int row = blockIdx.x, tid = threadIdx.x;
    float m = mask[row];
    size_t off = (size_t)row * DD + tid * 4;
    bf16x4 s0 = *(const bf16x4*)(P0 + off);
    bf16x4 s1 = *(const bf16x4*)(P1 + off);
    f32x4 bv = ((const f32x4*)bias)[tid];
    bf16x4 g4 = *(const bf16x4*)(proj + (size_t)row * NPROJ + tid * 4);
    f32x4 rv = ((const f32x4*)(res + (size_t)row * DD))[tid];
    f32x4 v;
    #pragma unroll
    for (int q = 0; q < 4; q++) {
        float sg = 1.0f / (1.0f + __expf(-(float)g4[q]));
        float sv = (float)s0[q] + (float)s1[q] + bv[q];
        v[q] = (rv[q] + sg * sv) * m;
    }
    ((f32x4*)(out1 + (size_t)row * DD))[tid] = v;
    // LN2
    float s = v[0] + v[1] + v[2] + v[3];
    float s2 = v[0]*v[0] + v[1]*v[1] + v[2]*v[2] + v[3]*v[3];
    #pragma unroll
    for (int off2 = 32; off2 > 0; off2 >>= 1) {
        s  += __shfl_xor(s,  off2, 64);
        s2 += __shfl_xor(s2, off2, 64);
    }
    __shared__ float rs[4], rs2[4];
    int wid = tid >> 6;
    if ((tid & 63) == 0) { rs[wid] = s; rs2[wid] = s2; }
    __syncthreads();
    s  = rs[0] + rs[1] + rs[2] + rs[3];
    s2 = rs2[0] + rs2[1] + rs2[2] + rs2[3];
    float mean = s * (1.0f / DD);
    float var  = s2 * (1.0f / DD) - mean * mean;
    float rstd = rsqrtf(var + 1e-5f);
    f32x4 gg = ((const f32x4*)g2)[tid];
    f32x4 bb = ((const f32x4*)b2v)[tid];
    bf16x4 h;
    #pragma unroll
    for (int q = 0; q < 4; q++)
        h[q] = (bf16)((v[q] - mean) * rstd * gg[q] + bb[q]);
    ((bf16x4*)(hbuf + (size_t)row * DD))[tid] = h;
}

// ---------------------------------------------------------------- final epilogue: out = (out1 + sum 4 bf16 partials + b2) * mask
__global__ __launch_bounds__(256) void epi_w2(
    float* __restrict__ d_out, const float* __restrict__ out1,
    const bf16* __restrict__ P0, const bf16* __restrict__ P1,
    const bf16* __restrict__ P2, const bf16* __restrict__ P3,
    const float* __restrict__ bias, const float* __restrict__ mask)
{
    int id = blockIdx.x * 256 + threadIdx.x;
    int row = id >> 8;
    float m = mask[row];
    bf16x4 a0 = ((const bf16x4*)P0)[id];
    bf16x4 a1 = ((const bf16x4*)P1)[id];
    bf16x4 a2 = ((const bf16x4*)P2)[id];
    bf16x4 a3 = ((const bf16x4*)P3)[id];
    f32x4 r = ((const f32x4*)out1)[id];
    f32x4 b = ((const f32x4*)bias)[id & 255];
    f32x4 o;
    #pragma unroll
    for (int q = 0; q < 4; q++) {
        float sv = (float)a0[q] + (float)a1[q] + (float)a2[q] + (float)a3[q];
        o[q] = (r[q] + sv + b[q]) * m;
    }
    ((f32x4*)d_out)[id] = o;
}

// ---------------------------------------------------------------- attention helpers
__device__ __forceinline__ float phi_f(float x) {
    return x > 0.f ? x + 1.f : __expf(x);   // elu(x)+1
}

// ---------------------------------------------------------------- mid fused
__global__ __launch_bounds__(256) void mid_fused(
    const bf16* __restrict__ x,
    const float* __restrict__ w_t, const float* __restrict__ b_t,
    const float* __restrict__ w_p, const float* __restrict__ b_p,
    bf16* __restrict__ cat,
    const bf16* __restrict__ proj, const float* __restrict__ mask,
    float* __restrict__ kvsum, float* __restrict__ kssum)
{
    __shared__ float s_ks[2][CHUNK][32], s_vs[2][CHUNK][32];   // 32 KB
    int blk = blockIdx.x, tid = threadIdx.x;
    if (blk < 1024) {
        // ---- dwconv ----
        int id = blk * 256 + tid;
        int cg = id & 127, rp = id >> 7;
        int c0 = cg * 8;
        int row0 = rp * 2;
        int t0 = row0 & (TT - 1);
        bf16x8 xw[16];
        #pragma unroll
        for (int j = 0; j < 16; j++) {
            int t = t0 - 14 + j;
            if (t >= 0)
                xw[j] = *(const bf16x8*)(x + (size_t)(row0 - 14 + j) * DD + c0);
            else
                #pragma unroll
                for (int q = 0; q < 8; q++) xw[j][q] = (bf16)0.f;
        }
        float y15[2][8], y3[2][8];
        #pragma unroll
        for (int q = 0; q < 8; q++) {
            float bp = b_p[c0 + q], bt = b_t[c0 + q];
            y15[0][q] = bp; y15[1][q] = bp;
            y3[0][q] = bt;  y3[1][q] = bt;
        }
        #pragma unroll
        for (int i = 0; i < 15; i++) {
            float wp[8];
            #pragma unroll
            for (int q = 0; q < 8; q++) wp[q] = w_p[(c0 + q) * 15 + i];
            #pragma unroll
            for (int rr = 0; rr < 2; rr++)
                #pragma unroll
                for (int q = 0; q < 8; q++)
                    y15[rr][q] = fmaf(wp[q], (float)xw[rr + i][q], y15[rr][q]);
        }
        #pragma unroll
        for (int i = 0; i < 3; i++) {
            float wt[8];
            #pragma unroll
            for (int q = 0; q < 8; q++) wt[q] = w_t[(c0 + q) * 3 + i];
            #pragma unroll
            for (int rr = 0; rr < 2; rr++)
                #pragma unroll
                for (int q = 0; q < 8; q++)
                    y3[rr][q] = fmaf(wt[q], (float)xw[rr + 12 + i][q], y3[rr][q]);
        }
        #pragma unroll
        for (int rr = 0; rr < 2; rr++) {
            bf16x8 o3, o15;
            #pragma unroll
            for (int q = 0; q < 8; q++) { o3[q] = (bf16)y3[rr][q]; o15[q] = (bf16)y15[rr][q]; }
            *(bf16x8*)(cat + (size_t)(row0 + rr) * CATD2 + 512 + c0)  = o3;
            *(bf16x8*)(cat + (size_t)(row0 + rr) * CATD2 + 1536 + c0) = o15;
        }
        return;
    }
    // ---- attn phase A ----
    int w = tid >> 6;
    if (w >= 2) return;
    int lane = tid & 63;
    int ci = (blk - 1024) * 2 + w;
    int c  = ci & (NCH - 1);
    int bh = ci >> 5;
    int b  = bh >> 4, hh = bh & (HH - 1);
    float (*ks)[32] = s_ks[w];
    float (*vs)[32] = s_vs[w];
    int row0 = b * TT + c * CHUNK;
    {
        int row = row0 + lane;
        float m = mask[row];
        const bf16* kp = proj + (size_t)row * NPROJ + DD + INNERD + hh * 32;
        const bf16* vp = kp + INNERD;
        #pragma unroll
        for (int s = 0; s < 4; s++) {
            bf16x8 k8 = *(const bf16x8*)(kp + s * 8);
            bf16x8 v8 = *(const bf16x8*)(vp + s * 8);
            #pragma unroll
            for (int q = 0; q < 8; q++) {
                ks[lane][s * 8 + q] = phi_f((float)k8[q]) * m;
                vs[lane][s * 8 + q] = (float)v8[q] * m;
            }
        }
    }
    int e = lane & 31, d0 = (lane >> 5) * 16;
    float kv[16], ksl[16];
    #pragma unroll
    for (int j = 0; j < 16; j++) { kv[j] = 0.f; ksl[j] = 0.f; }
    for (int t = 0; t < CHUNK; t++) {
        float ve = vs[t][e];
        f32x4 kr[4];
        #pragma unroll
        for (int s = 0; s < 4; s++) kr[s] = *(const f32x4*)&ks[t][d0 + s * 4];
        #pragma unroll
        for (int j = 0; j < 16; j++) {
            float kval = kr[j >> 2][j & 3];
            kv[j] = fmaf(kval, ve, kv[j]);
            ksl[j] += kval;
        }
    }
    size_t base = (size_t)ci * 1024;
    #pragma unroll
    for (int j = 0; j < 16; j++)
        kvsum[base + (size_t)(d0 + j) * 32 + e] = kv[j];
    if (e == 0) {
        #pragma unroll
        for (int j = 0; j < 16; j++)
            kssum[ci * 32 + d0 + j] = ksl[j];
    }
}

// Phase B: exclusive prefix over chunks — parallel (one scan per thread).
__global__ __launch_bounds__(256) void attn_prefix(
    const float* __restrict__ kvsum, const float* __restrict__ kssum,
    float* __restrict__ kvpref, float* __restrict__ kspref)
{
    int blk = blockIdx.x, tid = threadIdx.x;
    if (blk < 128) {
        int bh = blk >> 2;
        int de = (blk & 3) * 256 + tid;
        float run = 0.f;
        for (int c = 0; c < NCH; c++) {
            size_t a = (size_t)(bh * NCH + c) * 1024 + de;
            kvpref[a] = run;
            run += kvsum[a];
        }
        return;
    }
    int id = (blk - 128) * 256 + tid;
    int bh = id >> 5, d = id & 31;
    float r = 0.f;
    for (int c = 0; c < NCH; c++) {
        int a = (bh * NCH + c) * 32 + d;
        kspref[a] = r;
        r += kssum[a];
    }
}

// Phase C: in-chunk scan, LDS-resident. Writes attn output into cat[:,0:512).
__global__ __launch_bounds__(64) void attn_scan(
    const bf16* __restrict__ proj, const float* __restrict__ mask,
    const float* __restrict__ kvpref, const float* __restrict__ kspref,
    bf16* __restrict__ cat)
{
    int blk = blockIdx.x;
    int c  = blk & (NCH - 1);
    int bh = blk >> 5;
    int b  = bh >> 4, hh = bh & (HH - 1);
    int lane = threadIdx.x;
    __shared__ float qs[CHUNK][32], ks[CHUNK][32], vs[CHUNK][32];
    __shared__ float ms[CHUNK];
    int row0 = b * TT + c * CHUNK;
    {
        int row = row0 + lane;
        float m = mask[row];
        ms[lane] = m;
        const bf16* qp = proj + (size_t)row * NPROJ + DD + hh * 32;
        const bf16* kp = qp + INNERD;
        const bf16* vp = kp + INNERD;
        #pragma unroll
        for (int s = 0; s < 4; s++) {
            bf16x8 q8 = *(const bf16x8*)(qp + s * 8);
            bf16x8 k8 = *(const bf16x8*)(kp + s * 8);
            bf16x8 v8 = *(const bf16x8*)(vp + s * 8);
            #pragma unroll
            for (int q = 0; q < 8; q++) {
                qs[lane][s * 8 + q] = phi_f((float)q8[q]) * m;
                ks[lane][s * 8 + q] = phi_f((float)k8[q]) * m;
                vs[lane][s * 8 + q] = (float)v8[q] * m;
            }
        }
    }
    int e = lane & 31, d0 = (lane >> 5) * 16;
    float kv[16], ksl[16];
    size_t base = (size_t)blk * 1024;
    #pragma unroll
    for (int j = 0; j < 16; j++) kv[j] = kvpref[base + (size_t)(d0 + j) * 32 + e];
    #pragma unroll
    for (int j = 0; j < 16; j++) ksl[j] = kspref[blk * 32 + d0 + j];
    __syncthreads();
    for (int t = 0; t < CHUNK; t++) {
        float ve = vs[t][e];
        f32x4 kr[4], qr[4];
        #pragma unroll
        for (int s = 0; s < 4; s++) kr[s] = *(const f32x4*)&ks[t][d0 + s * 4];
        #pragma unroll
        for (int s = 0; s < 4; s++) qr[s] = *(const f32x4*)&qs[t][d0 + s * 4];
        float num0 = 0.f, num1 = 0.f, den0 = 0.f, den1 = 0.f;
        #pragma unroll
        for (int j = 0; j < 16; j++) {
            float kval = kr[j >> 2][j & 3], qval = qr[j >> 2][j & 3];
            kv[j]  = fmaf(kval, ve, kv[j]);
            ksl[j] += kval;
            if (j & 1) { num1 = fmaf(qval, kv[j], num1); den1 = fmaf(qval, ksl[j], den1); }
            else       { num0 = fmaf(qval, kv[j], num0); den0 = fmaf(qval, ksl[j], den0); }
        }
        float num = num0 + num1, den = den0 + den1;
        num += __shfl_xor(num, 32, 64);
        den += __shfl_xor(den, 32, 64);
        if (lane < 32)
            cat[(size_t)(row0 + t) * CATD2 + hh * 32 + e] =
                (bf16)(num / (den + 1e-6f) * ms[t]);
    }
}

// ---------------------------------------------------------------- launch
extern "C" void kernel_launch(void* const* d_in, const int* in_sizes, int n_in,
                              void* d_out, int out_size, void* d_ws, size_t ws_size,
                              hipStream_t stream)
{
    const float* inputs = (const float*)d_in[0];
    const float* mask   = (const float*)d_in[1];
    const float* ln1_g  = (const float*)d_in[2];
    const float* ln1_b  = (const float*)d_in[3];
    const float* W_in   = (const float*)d_in[4];
    const float* b_in   = (const float*)d_in[5];
    const float* W_c    = (const float*)d_in[6];
    const float* b_c    = (const float*)d_in[7];
    const float* w_t    = (const float*)d_in[8];
    const float* b_t    = (const float*)d_in[9];
    const float* w_p    = (const float*)d_in[10];
    const float* b_p    = (const float*)d_in[11];
    const float* W_mix  = (const float*)d_in[12];
    const float* b_mix  = (const float*)d_in[13];
    const float* ln2_g  = (const float*)d_in[14];
    const float* ln2_b  = (const float*)d_in[15];
    const float* W1     = (const float*)d_in[16];
    const float* b1     = (const float*)d_in[17];
    const float* W2     = (const float*)d_in[18];
    const float* b2     = (const float*)d_in[19];
    float* out = (float*)d_out;

    // workspace layout (MiB offsets):
    //   normed [0,8)  proj [8,28)  cat [28,48)  out1 [48,64)  hbuf [64,72)
    //   wt_in [72,77) wt_m0 [77,79) wt_comb [79,84) wt1 [84,92) wt2 [92,100)
    //   wc_b [100,101) bmix2
    // Aliases:
    //   ffn1 (32 MiB) = [0,32) = normed|proj|cat[0:4MiB]  (all dead by W1 GEMM)
    //   attn kv scratch aliases out1 (dead until epi_mix_ln2)
    //   mix partials: d_out (2 x 8 MiB bf16)
    //   W2 partials: disjoint from ffn1 [0,32): cat+4MiB -> abs [32,40),
    //   cat+12MiB -> abs [40,48), wt1, hbuf (both dead after W1 GEMM).
    char* p = (char*)d_ws;
    bf16* normed = (bf16*)p;  p += (size_t)MROWS * DD * 2;       // 8 MiB
    bf16* proj   = (bf16*)p;  p += (size_t)MROWS * NPROJ * 2;    // 20 MiB
    bf16* cat    = (bf16*)p;  p += (size_t)MROWS * CATD2 * 2;    // 20 MiB
    float* out1  = (float*)p; p += (size_t)MROWS * DD * 4;       // 16 MiB
    bf16* hbuf   = (bf16*)p;  p += (size_t)MROWS * DD * 2;       // 8 MiB
    bf16* wt_in  = (bf16*)p;  p += (size_t)NPROJ * DD * 2;       // 5 MiB
    bf16* wt_m0  = (bf16*)p;  p += (size_t)DD * DD * 2;          // 2 MiB
    bf16* wt_comb= (bf16*)p;  p += (size_t)DD * CATD2 * 2;       // 5 MiB
    bf16* wt1    = (bf16*)p;  p += (size_t)FFD * DD * 2;         // 8 MiB
    bf16* wt2    = (bf16*)p;  p += (size_t)DD * FFD * 2;         // 8 MiB
    bf16* wc_b   = (bf16*)p;  p += (size_t)INNERD * DD * 2;      // 1 MiB
    float* bmix2 = (float*)p; p += (size_t)DD * 4;               // 4 KiB
    bf16* ffn1   = (bf16*)d_ws;                  // alias [normed|proj|cat-head]
    float* kvsum = out1;                         // alias out1 region (attn)
    float* kvpref= kvsum  + (size_t)BH * NCH * 1024;
    float* kssum = kvpref + (size_t)BH * NCH * 1024;
    float* kspref= kssum  + (size_t)BH * NCH * 32;
    // split-K bf16 partials
    bf16*  m_p0  = (bf16*)d_out;
    bf16*  m_p1  = (bf16*)d_out + (size_t)MROWS * DD;
    bf16*  w2_p0 = (bf16*)((char*)cat + ((size_t)4  << 20));  // abs [32,40) MiB
    bf16*  w2_p1 = (bf16*)((char*)cat + ((size_t)12 << 20));  // abs [40,48) MiB
    bf16*  w2_p2 = wt1;
    bf16*  w2_p3 = hbuf;

    // 1. fused prep: bmix2 fold (first!) + W_c cast + LN1 + weight transposes
    prep_fused<<<16 + 512 + MROWS + 13824, 256, 0, stream>>>(
        inputs, ln1_g, ln1_b, normed,
        W_in, wt_in, W_mix, wt_m0, wt_comb, W1, wt1, W2, wt2,
        W_c, wc_b, b_c, b_mix, bmix2);
    // 2. proj = normed @ W_in + b_in  (+ Wcm GEMM riding in by==20 row)
    gemm_proj2<<<dim3(MROWS/128, NPROJ/128 + 1), 256, 0, stream>>>(
        normed, wt_in, b_in, proj, wt_m0, wc_b, wt_comb);
    // 3. fused dwconv + attn phase A
    mid_fused<<<1024 + 512, 256, 0, stream>>>(
        normed, w_t, b_t, w_p, b_p, cat, proj, mask, kvsum, kssum);
    // 4-5. prefix + scan (scan writes cat[:,0:512))
    attn_prefix<<<132, 256, 0, stream>>>(kvsum, kssum, kvpref, kspref);
    attn_scan  <<<BH * NCH, 64, 0, stream>>>(proj, mask, kvpref, kspref, cat);
    // 6. mix split-2 bf16 partials: cat(2560) @ wt_comb
    gemm_mfma<4><<<dim3(MROWS/128, DD/128, 2), 256, 0, stream>>>(
        cat, CATD2, wt_comb, CATD2, nullptr, nullptr, DD, CATD2 / 2,
        Part4{m_p0, m_p1, nullptr, nullptr});
    // 7. out1 = (inputs + sigmoid(gate)*(P0+P1+bmix2))*mask ; hbuf = LN2(out1)
    epi_mix_ln2<<<MROWS, 256, 0, stream>>>(m_p0, m_p1, bmix2, proj, inputs,
                                           mask, ln2_g, ln2_b, out1, hbuf);
    // 8. ffn1 = gelu(hbuf @ W1 + b1)
    gemm_mfma<1><<<dim3(MROWS/128, FFD/128), 256, 0, stream>>>(
        hbuf, DD, wt1, DD, b1, ffn1, FFD, DD, Part4{});
    // 9. W2 split-4 bf16 partials (partials disjoint from ffn1!)
    gemm_mfma<4><<<dim3(MROWS/128, DD/128, 4), 256, 0, stream>>>(
        ffn1, FFD, wt2, FFD, nullptr, nullptr, DD, FFD / 4,
        Part4{w2_p0, w2_p1, w2_p2, w2_p3});
    // 10. out = (out1 + sum P + b2) * mask
    epi_w2<<<MROWS * DD / 4 / 256, 256, 0, stream>>>(out, out1, w2_p0, w2_p1,
                                                     w2_p2, w2_p3, b2, mask);
}